// Round 2
// baseline (802.298 us; speedup 1.0000x reference)
//
#include <hip/hip_runtime.h>
#include <math.h>

// Problem shape (fixed by the reference): B=32, T=4096, H=1024, fp32.
#define B_ 32
#define T_ 4096
#define H_ 1024
#define H4_ 256          // float4 per (b,t) row
#define NCHUNK_ 64       // t-chunks; T_/NCHUNK_ = 64 t per chunk
#define TPC_ 64          // t per chunk

// ---------------------------------------------------------------------------
// Kernel 1: partial scores.  pscores[t*B + b] = dot(s[b,:], eh[b,t,:]).
// grid (NCHUNK_, B_); block = 256 thr = 4 waves. Each block streams one
// CONTIGUOUS 256 KiB slab eh[b, chunk*64 .. chunk*64+63, :]. s[b,:] staged in
// LDS once (removes the old 512 MiB of decoder_state re-reads). Wave w
// handles t_local = w + 4*i; per t: 4 independent float4 loads per lane.
// ---------------------------------------------------------------------------
__global__ __launch_bounds__(256) void pscores_kernel(
    const float4* __restrict__ s4, const float4* __restrict__ eh4,
    float* __restrict__ pscores)
{
    const int chunk = blockIdx.x;
    const int b     = blockIdx.y;
    const int tid   = threadIdx.x;
    const int lane  = tid & 63;
    const int w     = tid >> 6;

    __shared__ float4 sS[H4_];
    sS[tid] = s4[b * H4_ + tid];
    __syncthreads();
    const float4 s0 = sS[lane];
    const float4 s1 = sS[lane + 64];
    const float4 s2 = sS[lane + 128];
    const float4 s3 = sS[lane + 192];

    const float4* ehb = eh4 + ((size_t)b * T_ + (size_t)chunk * TPC_) * H4_;

#pragma unroll 4
    for (int i = 0; i < TPC_ / 4; ++i) {
        const int tl = w + 4 * i;
        const float4* row = ehb + (size_t)tl * H4_;
        float4 e0 = row[lane];
        float4 e1 = row[lane + 64];
        float4 e2 = row[lane + 128];
        float4 e3 = row[lane + 192];
        float d = e0.x * s0.x + e0.y * s0.y + e0.z * s0.z + e0.w * s0.w
                + e1.x * s1.x + e1.y * s1.y + e1.z * s1.z + e1.w * s1.w
                + e2.x * s2.x + e2.y * s2.y + e2.z * s2.z + e2.w * s2.w
                + e3.x * s3.x + e3.y * s3.y + e3.z * s3.z + e3.w * s3.w;
        for (int off = 32; off > 0; off >>= 1)
            d += __shfl_down(d, off, 64);
        if (lane == 0)
            pscores[(chunk * TPC_ + tl) * B_ + b] = d;
    }
}

// ---------------------------------------------------------------------------
// Kernel 2: fold b-partials + softmax over T.  One block, 256 thr x 16 t.
// pscores is [T, B] so each t's 32 partials are 8 contiguous float4.
// ---------------------------------------------------------------------------
__global__ __launch_bounds__(256) void softmax_kernel(
    const float4* __restrict__ ps4, float* __restrict__ dist)
{
    const int tid = threadIdx.x;
    __shared__ float redm[4];
    __shared__ float reds[4];

    float v[16];
    float m = -INFINITY;
#pragma unroll
    for (int k = 0; k < 16; ++k) {
        const int t = tid + k * 256;
        const float4* p = ps4 + (size_t)t * (B_ / 4);
        float s = 0.f;
#pragma unroll
        for (int j = 0; j < B_ / 4; ++j) {
            float4 q = p[j];
            s += q.x + q.y + q.z + q.w;
        }
        v[k] = s;
        m = fmaxf(m, s);
    }
    for (int off = 32; off > 0; off >>= 1)
        m = fmaxf(m, __shfl_down(m, off, 64));
    if ((tid & 63) == 0) redm[tid >> 6] = m;
    __syncthreads();
    const float M = fmaxf(fmaxf(redm[0], redm[1]), fmaxf(redm[2], redm[3]));

    float e[16];
    float sum = 0.f;
#pragma unroll
    for (int k = 0; k < 16; ++k) {
        e[k] = expf(v[k] - M);
        sum += e[k];
    }
    for (int off = 32; off > 0; off >>= 1)
        sum += __shfl_down(sum, off, 64);
    if ((tid & 63) == 0) reds[tid >> 6] = sum;
    __syncthreads();
    const float L = reds[0] + reds[1] + reds[2] + reds[3];
    const float inv = 1.f / L;
#pragma unroll
    for (int k = 0; k < 16; ++k)
        dist[tid + k * 256] = e[k] * inv;
}

// ---------------------------------------------------------------------------
// Kernel 3: partial context. grid (NCHUNK_, B_); contiguous 256 KiB stream
// per block. Chunk order REVERSED vs kernel 1 to harvest L3 leftovers.
// ---------------------------------------------------------------------------
__global__ __launch_bounds__(256) void context_kernel(
    const float4* __restrict__ eh4, const float* __restrict__ dist,
    float4* __restrict__ part4)
{
    const int chunk = (NCHUNK_ - 1) - blockIdx.x;
    const int b     = blockIdx.y;
    const int tid   = threadIdx.x;  // h4 index

    const float4* base  = eh4 + ((size_t)b * T_ + (size_t)chunk * TPC_) * H4_ + tid;
    const float*  wbase = dist + chunk * TPC_;

    float4 acc = make_float4(0.f, 0.f, 0.f, 0.f);
#pragma unroll 8
    for (int i = 0; i < TPC_; ++i) {
        float  w = wbase[i];          // wave-uniform -> scalar load
        float4 e = base[(size_t)i * H4_];
        acc.x += w * e.x;
        acc.y += w * e.y;
        acc.z += w * e.z;
        acc.w += w * e.w;
    }
    part4[((size_t)chunk * B_ + b) * H4_ + tid] = acc;
}

// ---------------------------------------------------------------------------
// Kernel 4: out[b,h] = sum_chunk partial[chunk,b,h].  8192 float4 outputs.
// ---------------------------------------------------------------------------
__global__ __launch_bounds__(256) void reduce_kernel(
    const float4* __restrict__ part4, float4* __restrict__ out4)
{
    const int o4 = blockIdx.x * 256 + threadIdx.x;  // [0, 8192)
    float4 acc = make_float4(0.f, 0.f, 0.f, 0.f);
#pragma unroll 8
    for (int c = 0; c < NCHUNK_; ++c) {
        float4 p = part4[(size_t)c * (B_ * H4_) + o4];
        acc.x += p.x;
        acc.y += p.y;
        acc.z += p.z;
        acc.w += p.w;
    }
    out4[o4] = acc;
}

extern "C" void kernel_launch(void* const* d_in, const int* in_sizes, int n_in,
                              void* d_out, int out_size, void* d_ws, size_t ws_size,
                              hipStream_t stream) {
    const float* s  = (const float*)d_in[0];   // [B, H]
    const float* eh = (const float*)d_in[1];   // [B, T, H]

    float* ws      = (float*)d_ws;
    float* pscores = ws;                           // T_*B_ floats (512 KiB)
    float* dist    = ws + (size_t)T_ * B_;         // T_ floats
    float4* part4  = (float4*)(dist + T_);         // NCHUNK_*B_*H_ floats = 8 MiB

    pscores_kernel<<<dim3(NCHUNK_, B_), 256, 0, stream>>>(
        (const float4*)s, (const float4*)eh, pscores);
    softmax_kernel<<<1, 256, 0, stream>>>((const float4*)pscores, dist);
    context_kernel<<<dim3(NCHUNK_, B_), 256, 0, stream>>>(
        (const float4*)eh, dist, part4);
    reduce_kernel<<<(B_ * H4_) / 256, 256, 0, stream>>>(part4, (float4*)d_out);
}

// Round 3
// 700.170 us; speedup vs baseline: 1.1459x; 1.1459x over previous
//
#include <hip/hip_runtime.h>
#include <math.h>

// Problem shape (fixed by reference): B=32, T=4096, H=1024, fp32.
#define B_  32
#define T_  4096
#define H_  1024
#define H4_ 256            // float4 per (b,t) row
#define G_  256            // pass-1 workgroups (1 per CU)
#define TPG_ (T_ / G_)     // 16 t per workgroup
#define BH4_ (B_ * H4_)    // 8192 float4 per t-slice / per output

// ---------------------------------------------------------------------------
// Pass 1: single-pass online-softmax attention.
// Workgroup g owns t in [g*16, g*16+16). 1024 threads: thread (b=tid>>5,
// hb=tid&31) owns 8 float4 lanes (h4 = hb+32j). Per t: load e (8 float4),
// dot with resident s-fragment, block-reduce to score_t, online-softmax
// rescale of the register accumulator. eh is read EXACTLY ONCE (512 MiB).
// Partials (m,l,O) per group written for the combine pass (32 MiB).
// VGPR budget: s(32)+e(32)+acc(32)+misc ~= 112 <= 128 -> 16 waves/CU.
// ---------------------------------------------------------------------------
__global__ __launch_bounds__(1024) void flash_kernel(
    const float4* __restrict__ s4, const float4* __restrict__ eh4,
    float4* __restrict__ Og4, float* __restrict__ mg, float* __restrict__ lg)
{
    const int g    = blockIdx.x;
    const int tid  = threadIdx.x;
    const int lane = tid & 63;
    const int w    = tid >> 6;   // wave 0..15
    const int b    = tid >> 5;   // 0..31
    const int hb   = tid & 31;   // h4 base

    __shared__ float redw[16];
    __shared__ float sc_sh;

    float4 sreg[8];
#pragma unroll
    for (int j = 0; j < 8; ++j)
        sreg[j] = s4[b * H4_ + hb + 32 * j];

    const float4* ep = eh4 + ((size_t)b * T_ + (size_t)g * TPG_) * H4_ + hb;

    float4 acc[8];
#pragma unroll
    for (int j = 0; j < 8; ++j) acc[j] = make_float4(0.f, 0.f, 0.f, 0.f);
    float m = -INFINITY, l = 0.f;

    for (int i = 0; i < TPG_; ++i) {
        float4 e[8];
#pragma unroll
        for (int j = 0; j < 8; ++j) e[j] = ep[32 * j];
        ep += H4_;

        float p = 0.f;
#pragma unroll
        for (int j = 0; j < 8; ++j)
            p += e[j].x * sreg[j].x + e[j].y * sreg[j].y
               + e[j].z * sreg[j].z + e[j].w * sreg[j].w;

        for (int off = 32; off > 0; off >>= 1)
            p += __shfl_down(p, off, 64);
        if (lane == 0) redw[w] = p;
        __syncthreads();
        if (w == 0) {
            float q = (lane < 16) ? redw[lane] : 0.f;
            q += __shfl_down(q, 8, 64);
            q += __shfl_down(q, 4, 64);
            q += __shfl_down(q, 2, 64);
            q += __shfl_down(q, 1, 64);
            if (lane == 0) sc_sh = q;
        }
        __syncthreads();
        const float score = sc_sh;

        const float mn    = fmaxf(m, score);
        const float alpha = __expf(m - mn);      // first iter: exp(-inf)=0
        const float wgt   = __expf(score - mn);
        l = l * alpha + wgt;
#pragma unroll
        for (int j = 0; j < 8; ++j) {
            acc[j].x = acc[j].x * alpha + wgt * e[j].x;
            acc[j].y = acc[j].y * alpha + wgt * e[j].y;
            acc[j].z = acc[j].z * alpha + wgt * e[j].z;
            acc[j].w = acc[j].w * alpha + wgt * e[j].w;
        }
        m = mn;
    }

    float4* op = Og4 + (size_t)g * BH4_ + b * H4_ + hb;
#pragma unroll
    for (int j = 0; j < 8; ++j) op[32 * j] = acc[j];
    if (tid == 0) { mg[g] = m; lg[g] = l; }
}

// ---------------------------------------------------------------------------
// Pass 2: combine G_ partials. 128 blocks x 64 thr; each block computes
// (M, L) redundantly from mg/lg (2 KiB), builds weights in LDS, then folds
// its 64 output float4 across all 256 group slabs (coalesced, 32 MiB total).
// ---------------------------------------------------------------------------
__global__ __launch_bounds__(64) void combine_kernel(
    const float4* __restrict__ Og4, const float* __restrict__ mg,
    const float* __restrict__ lg, float4* __restrict__ out4)
{
    const int tid = threadIdx.x;   // 0..63
    __shared__ float wsh[G_];

    float mv[4];
    float M = -INFINITY;
#pragma unroll
    for (int j = 0; j < 4; ++j) {
        mv[j] = mg[tid + 64 * j];
        M = fmaxf(M, mv[j]);
    }
    for (int off = 32; off > 0; off >>= 1)
        M = fmaxf(M, __shfl_down(M, off, 64));
    M = __shfl(M, 0, 64);

    float Ls = 0.f;
#pragma unroll
    for (int j = 0; j < 4; ++j)
        Ls += lg[tid + 64 * j] * __expf(mv[j] - M);
    for (int off = 32; off > 0; off >>= 1)
        Ls += __shfl_down(Ls, off, 64);
    Ls = __shfl(Ls, 0, 64);
    const float invL = 1.f / Ls;

#pragma unroll
    for (int j = 0; j < 4; ++j)
        wsh[tid + 64 * j] = __expf(mv[j] - M) * invL;
    __syncthreads();

    const int o4 = blockIdx.x * 64 + tid;
    float4 acc = make_float4(0.f, 0.f, 0.f, 0.f);
    for (int gg = 0; gg < G_; gg += 4) {
        float4 a0 = Og4[(size_t)(gg + 0) * BH4_ + o4];
        float4 a1 = Og4[(size_t)(gg + 1) * BH4_ + o4];
        float4 a2 = Og4[(size_t)(gg + 2) * BH4_ + o4];
        float4 a3 = Og4[(size_t)(gg + 3) * BH4_ + o4];
        float w0 = wsh[gg], w1 = wsh[gg + 1], w2 = wsh[gg + 2], w3 = wsh[gg + 3];
        acc.x += w0 * a0.x + w1 * a1.x + w2 * a2.x + w3 * a3.x;
        acc.y += w0 * a0.y + w1 * a1.y + w2 * a2.y + w3 * a3.y;
        acc.z += w0 * a0.z + w1 * a1.z + w2 * a2.z + w3 * a3.z;
        acc.w += w0 * a0.w + w1 * a1.w + w2 * a2.w + w3 * a3.w;
    }
    out4[o4] = acc;
}

extern "C" void kernel_launch(void* const* d_in, const int* in_sizes, int n_in,
                              void* d_out, int out_size, void* d_ws, size_t ws_size,
                              hipStream_t stream) {
    const float* s  = (const float*)d_in[0];   // [B, H]
    const float* eh = (const float*)d_in[1];   // [B, T, H]

    float4* Og4 = (float4*)d_ws;                       // G_*B_*H_ floats = 32 MiB
    float*  mg  = (float*)(Og4 + (size_t)G_ * BH4_);   // G_ floats
    float*  lg  = mg + G_;                             // G_ floats

    flash_kernel<<<G_, 1024, 0, stream>>>(
        (const float4*)s, (const float4*)eh, Og4, mg, lg);
    combine_kernel<<<BH4_ / 64, 64, 0, stream>>>(
        Og4, mg, lg, (float4*)d_out);
}